// Round 2
// baseline (2128.872 us; speedup 1.0000x reference)
//
#include <hip/hip_runtime.h>
#include <hip/hip_bf16.h>
#include <math.h>

// ---------------- constants ----------------
#define BATCH 2
#define NIN   1024
#define NSEQ  2048
#define DIMC  512
#define NH    8
#define DHD   64
#define MLM   17
#define LBLK  125
#define SEQ   2117      // 1 + 2116
#define NPAD  2125      // SEQ + 8
#define PAD0  8
#define HS    46
#define NPIX  2116      // 46*46
#define AWSZ  ((size_t)BATCH*NH*NPAD*NPAD)   // 72,250,000

// ---------------- generic tiled GEMM: C = A(MxK) @ B(KxN) (+bias)(+relu) ----------------
// N multiple of 64, K multiple of 16, M arbitrary (guarded).
__global__ __launch_bounds__(256) void gemm_kernel(const float* __restrict__ A, const float* __restrict__ B,
                             const float* __restrict__ bias, float* __restrict__ C,
                             int Mn, int Nn, int Kn, int relu)
{
    __shared__ float As[64][17];
    __shared__ float Bs[16][64];
    int tid = threadIdx.x;
    int row0 = blockIdx.y * 64;
    int col0 = blockIdx.x * 64;
    int ty = tid / 16, tx = tid % 16;
    float acc[4][4];
    #pragma unroll
    for (int u=0;u<4;++u)
        #pragma unroll
        for (int v=0;v<4;++v) acc[u][v]=0.f;

    for (int k0 = 0; k0 < Kn; k0 += 16) {
        #pragma unroll
        for (int i = tid; i < 64*16; i += 256) {
            int r = i >> 4, c = i & 15;
            int gr = row0 + r;
            As[r][c] = (gr < Mn) ? A[(size_t)gr * Kn + k0 + c] : 0.f;
        }
        #pragma unroll
        for (int i = tid; i < 16*64; i += 256) {
            int r = i >> 6, c = i & 63;
            Bs[r][c] = B[(size_t)(k0 + r) * Nn + col0 + c];
        }
        __syncthreads();
        #pragma unroll
        for (int kk = 0; kk < 16; ++kk) {
            float a[4], bb[4];
            #pragma unroll
            for (int u=0;u<4;++u) a[u] = As[ty*4+u][kk];
            #pragma unroll
            for (int v=0;v<4;++v) bb[v] = Bs[kk][tx*4+v];
            #pragma unroll
            for (int u=0;u<4;++u)
                #pragma unroll
                for (int v=0;v<4;++v) acc[u][v] += a[u]*bb[v];
        }
        __syncthreads();
    }
    for (int u=0;u<4;++u) {
        int r = row0 + ty*4+u;
        if (r >= Mn) continue;
        for (int v=0;v<4;++v) {
            int c = col0 + tx*4+v;
            float val = acc[u][v];
            if (bias) val += bias[c];
            if (relu) val = fmaxf(val, 0.f);
            C[(size_t)r * Nn + c] = val;
        }
    }
}

// ---------------- build h: cls + fc1out + wrap ----------------
__global__ void buildh_kernel(const float* __restrict__ h0, const float* __restrict__ cls,
                              float* __restrict__ h)
{
    size_t e = (size_t)blockIdx.x*256 + threadIdx.x;
    if (e >= (size_t)BATCH*SEQ*DIMC) return;
    int c = e % DIMC; size_t r = e / DIMC;
    int t = r % SEQ; int b = r / SEQ;
    float val;
    if (t == 0) val = cls[c];
    else {
        int n = t - 1;
        if (n >= NSEQ) n -= NSEQ;
        val = h0[((size_t)(b*NSEQ + n))*DIMC + c];
    }
    h[e] = val;
}

// ---------------- LayerNorm rows of h -> padded xp (rows 0..7 zero) ----------------
__global__ void ln_pad_kernel(const float* __restrict__ h, const float* __restrict__ g,
                              const float* __restrict__ bta, float* __restrict__ xp)
{
    int r = blockIdx.x; int b = blockIdx.y; int t = threadIdx.x; // block 256
    float* orow = &xp[((size_t)(b*NPAD + r))*DIMC];
    if (r < PAD0) { orow[t] = 0.f; orow[t+256] = 0.f; return; }
    const float* x = &h[((size_t)(b*SEQ + r-PAD0))*DIMC];
    __shared__ float red[256];
    float x0 = x[t], x1 = x[t+256];
    red[t] = x0 + x1; __syncthreads();
    for (int s=128;s>0;s>>=1){ if(t<s) red[t]+=red[t+s]; __syncthreads(); }
    float mu = red[0] * (1.f/512.f); __syncthreads();
    float d0 = x0-mu, d1 = x1-mu;
    red[t] = d0*d0 + d1*d1; __syncthreads();
    for (int s=128;s>0;s>>=1){ if(t<s) red[t]+=red[t+s]; __syncthreads(); }
    float rstd = 1.0f / sqrtf(red[0]*(1.f/512.f) + 1e-5f);
    orow[t]     = d0*rstd*g[t]     + bta[t];
    orow[t+256] = d1*rstd*g[t+256] + bta[t+256];
}

// ---------------- split qkv into head-major q(scaled),k,v ----------------
__global__ void split_heads_kernel(const float* __restrict__ qkv, float* __restrict__ q,
                                   float* __restrict__ k, float* __restrict__ v)
{
    size_t idx = (size_t)blockIdx.x*256 + threadIdx.x;
    if (idx >= (size_t)BATCH*NH*NPAD*DHD) return;
    int d = idx % DHD; size_t r = idx / DHD;
    int i = r % NPAD; r /= NPAD;
    int h = r % NH; int b = r / NH;
    size_t src = ((size_t)(b*NPAD + i))*1536 + h*DHD + d;
    q[idx] = qkv[src] * 0.125f;
    k[idx] = qkv[src + 512];
    v[idx] = qkv[src + 1024];
}

// ---------------- landmarks: mean over 125-blocks ----------------
__global__ void landmark_kernel(const float* __restrict__ q, const float* __restrict__ k,
                                float* __restrict__ ql, float* __restrict__ kl)
{
    int m = blockIdx.x, h = blockIdx.y, b = blockIdx.z, d = threadIdx.x; // 64 thr
    int bh = b*NH + h;
    size_t base = ((size_t)bh*NPAD + m*LBLK)*DHD + d;
    float sq = 0.f, sk = 0.f;
    for (int r=0;r<LBLK;++r){ sq += q[base + (size_t)r*DHD]; sk += k[base + (size_t)r*DHD]; }
    size_t o = ((size_t)bh*MLM + m)*DHD + d;
    ql[o] = sq / 125.f; kl[o] = sk / 125.f;
}

// ---------------- a1 = softmax(q @ kl^T), rows of 17 ----------------
__global__ void a1_kernel(const float* __restrict__ q, const float* __restrict__ kl,
                          float* __restrict__ a1)
{
    int i = blockIdx.x, h = blockIdx.y, b = blockIdx.z;
    int bh = b*NH + h; int lane = threadIdx.x; // 64
    __shared__ float qrow[64];
    __shared__ float dots[MLM];
    qrow[lane] = q[((size_t)bh*NPAD + i)*DHD + lane];
    __syncthreads();
    if (lane < MLM) {
        const float* krow = &kl[((size_t)bh*MLM + lane)*DHD];
        float acc = 0.f;
        for (int d=0; d<DHD; ++d) acc += qrow[d]*krow[d];
        dots[lane] = acc;
    }
    __syncthreads();
    if (lane < MLM) {
        float mx = -1e30f;
        for (int u=0;u<MLM;++u) mx = fmaxf(mx, dots[u]);
        float s = 0.f;
        for (int u=0;u<MLM;++u) s += expf(dots[u]-mx);
        a1[((size_t)bh*NPAD + i)*MLM + lane] = expf(dots[lane]-mx)/s;
    }
}

// ---------------- a2 = softmax(ql @ kl^T), 17x17 per (b,h) ----------------
__global__ void a2_kernel(const float* __restrict__ ql, const float* __restrict__ kl,
                          float* __restrict__ a2)
{
    int bh = blockIdx.x; int t = threadIdx.x; // 320
    __shared__ float s[MLM*MLM];
    if (t < MLM*MLM) {
        int m = t/MLM, j = t%MLM;
        const float* qr = &ql[((size_t)bh*MLM+m)*DHD];
        const float* kr = &kl[((size_t)bh*MLM+j)*DHD];
        float acc=0.f; for(int d=0;d<DHD;++d) acc += qr[d]*kr[d];
        s[t] = acc;
    }
    __syncthreads();
    if (t < MLM*MLM) {
        int m = t/MLM;
        float mx=-1e30f; for(int u=0;u<MLM;++u) mx=fmaxf(mx, s[m*MLM+u]);
        float sm=0.f; for(int u=0;u<MLM;++u) sm += expf(s[m*MLM+u]-mx);
        a2[(size_t)bh*MLM*MLM + t] = expf(s[t]-mx)/sm;
    }
}

// ---------------- a3 = softmax(ql @ k^T), rows of 2125 ----------------
__global__ void a3_kernel(const float* __restrict__ ql, const float* __restrict__ k,
                          float* __restrict__ a3)
{
    int m = blockIdx.x, h = blockIdx.y, b = blockIdx.z;
    int bh = b*NH + h; int tid = threadIdx.x; // 256
    __shared__ float qlrow[64];
    __shared__ float buf[NPAD];
    __shared__ float red[256];
    if (tid < 64) qlrow[tid] = ql[((size_t)bh*MLM+m)*DHD + tid];
    __syncthreads();
    for (int j = tid; j < NPAD; j += 256) {
        const float* kr = &k[((size_t)bh*NPAD + j)*DHD];
        float acc = 0.f;
        for (int d=0; d<DHD; ++d) acc += qlrow[d]*kr[d];
        buf[j] = acc;
    }
    __syncthreads();
    float mx = -1e30f;
    for (int j = tid; j < NPAD; j += 256) mx = fmaxf(mx, buf[j]);
    red[tid] = mx; __syncthreads();
    for (int s=128;s>0;s>>=1){ if(tid<s) red[tid]=fmaxf(red[tid],red[tid+s]); __syncthreads(); }
    mx = red[0]; __syncthreads();
    float sm = 0.f;
    for (int j = tid; j < NPAD; j += 256) sm += expf(buf[j]-mx);
    red[tid] = sm; __syncthreads();
    for (int s=128;s>0;s>>=1){ if(tid<s) red[tid]+=red[tid+s]; __syncthreads(); }
    sm = red[0];
    for (int j = tid; j < NPAD; j += 256)
        a3[((size_t)bh*MLM+m)*NPAD + j] = expf(buf[j]-mx)/sm;
}

// ---------------- pinv init scale (GLOBAL max over b,h) ----------------
__global__ void pinv_scale_kernel(const float* __restrict__ a2, float* __restrict__ scal)
{
    int t = threadIdx.x; // 512
    __shared__ float red[512];
    float rs = -1e30f, cs = -1e30f;
    if (t < BATCH*NH*MLM) {
        int bh = t/MLM, i = t%MLM;
        const float* x = &a2[(size_t)bh*MLM*MLM];
        float r=0.f, c=0.f;
        for (int j=0;j<MLM;++j){ r += fabsf(x[i*MLM+j]); c += fabsf(x[j*MLM+i]); }
        rs = r; cs = c;
    }
    red[t] = rs; __syncthreads();
    for (int s=256;s>0;s>>=1){ if(t<s) red[t]=fmaxf(red[t],red[t+s]); __syncthreads(); }
    float m1 = red[0]; __syncthreads();
    red[t] = cs; __syncthreads();
    for (int s=256;s>0;s>>=1){ if(t<s) red[t]=fmaxf(red[t],red[t+s]); __syncthreads(); }
    if (t==0) scal[0] = 1.f/(m1*red[0]);
}

// ---------------- pinv iterations, per (b,h) in LDS ----------------
__global__ void pinv_kernel(const float* __restrict__ a2, const float* __restrict__ scal,
                            float* __restrict__ a2i)
{
    int bh = blockIdx.x; int t = threadIdx.x; // 320
    __shared__ float x[289], z[289], xz[289], w1[289], w2[289];
    int i = t/MLM, j = t%MLM;
    bool act = t < MLM*MLM;
    if (act) x[t] = a2[(size_t)bh*MLM*MLM + t];
    __syncthreads();
    if (act) z[t] = x[j*MLM+i] * scal[0];
    __syncthreads();
    for (int it=0; it<6; ++it) {
        if (act){ float a=0.f; for(int k2=0;k2<MLM;++k2) a += x[i*MLM+k2]*z[k2*MLM+j]; xz[t]=a; }
        __syncthreads();
        if (act){ w1[t] = (i==j?7.f:0.f) - xz[t]; }
        __syncthreads();
        if (act){ float a=0.f; for(int k2=0;k2<MLM;++k2) a += xz[i*MLM+k2]*w1[k2*MLM+j]; w2[t]=a; }
        __syncthreads();
        if (act){ w1[t] = (i==j?15.f:0.f) - w2[t]; }
        __syncthreads();
        if (act){ float a=0.f; for(int k2=0;k2<MLM;++k2) a += xz[i*MLM+k2]*w1[k2*MLM+j]; w2[t]=a; }
        __syncthreads();
        if (act){ w1[t] = (i==j?13.f:0.f) - w2[t]; }
        __syncthreads();
        if (act){ float a=0.f; for(int k2=0;k2<MLM;++k2) a += z[i*MLM+k2]*w1[k2*MLM+j]; w2[t]=0.25f*a; }
        __syncthreads();
        if (act) z[t] = w2[t];
        __syncthreads();
    }
    if (act) a2i[(size_t)bh*MLM*MLM + t] = z[t];
}

// ---------------- left = a1 @ a2i ----------------
__global__ void left_kernel(const float* __restrict__ a1, const float* __restrict__ a2i,
                            float* __restrict__ left)
{
    int bh = blockIdx.z*NH + blockIdx.y;
    __shared__ float zi[289];
    int t = threadIdx.x; // 256
    for (int u=t; u<289; u+=256) zi[u] = a2i[(size_t)bh*289+u];
    __syncthreads();
    int e = blockIdx.x*256 + t;
    if (e < NPAD*MLM) {
        int i = e/MLM, j = e%MLM;
        const float* ar = &a1[((size_t)bh*NPAD + i)*MLM];
        float acc=0.f;
        for (int k2=0;k2<MLM;++k2) acc += ar[k2]*zi[k2*MLM+j];
        left[((size_t)bh*NPAD+i)*MLM + j] = acc;
    }
}

// ---------------- a3v = a3 @ v ----------------
__global__ void a3v_kernel(const float* __restrict__ a3, const float* __restrict__ v,
                           float* __restrict__ a3v)
{
    int m = blockIdx.x, h = blockIdx.y, b = blockIdx.z, d = threadIdx.x; // 64
    int bh = b*NH + h;
    const float* ar = &a3[((size_t)bh*MLM+m)*NPAD];
    const float* vb = &v[(size_t)bh*NPAD*DHD + d];
    float acc = 0.f;
    for (int j=0;j<NPAD;++j) acc += ar[j]*vb[(size_t)j*DHD];
    a3v[((size_t)bh*MLM+m)*DHD + d] = acc;
}

// ---------------- headout = left @ a3v + depthwise res conv(v), into (b,i,h*d) ----------------
__global__ void headout_kernel(const float* __restrict__ left, const float* __restrict__ a3v,
                               const float* __restrict__ v, const float* __restrict__ res_w,
                               float* __restrict__ hout)
{
    int i = blockIdx.x, h = blockIdx.y, b = blockIdx.z, t = threadIdx.x; // 64
    int bh = b*NH + h;
    __shared__ float lrow[MLM];
    __shared__ float rw[33];
    if (t < MLM) lrow[t] = left[((size_t)bh*NPAD+i)*MLM+t];
    if (t < 33)  rw[t] = res_w[h*33 + t];
    __syncthreads();
    float acc = 0.f;
    for (int m2=0;m2<MLM;++m2) acc += lrow[m2]*a3v[((size_t)bh*MLM+m2)*DHD+t];
    for (int s=0;s<33;++s) {
        int ii = i + s - 16;
        if (ii >= 0 && ii < NPAD) acc += rw[s]*v[((size_t)bh*NPAD+ii)*DHD+t];
    }
    hout[((size_t)(b*NPAD+i))*DIMC + h*DHD + t] = acc;
}

// ---------------- attn map write: aw = left @ a3 (to d_out) ----------------
__global__ void attn_out_kernel(const float* __restrict__ left, const float* __restrict__ a3,
                                float* __restrict__ aw)
{
    int bh = blockIdx.z; int i = blockIdx.y; int j0 = blockIdx.x*256;
    int t = threadIdx.x;
    __shared__ float lrow[MLM];
    if (t < MLM) lrow[t] = left[((size_t)bh*NPAD+i)*MLM+t];
    __syncthreads();
    int j = j0 + t;
    if (j < NPAD) {
        float acc = 0.f;
        for (int k2=0;k2<MLM;++k2) acc += lrow[k2]*a3[((size_t)bh*MLM+k2)*NPAD + j];
        aw[((size_t)bh*NPAD + i)*NPAD + j] = acc;
    }
}

// ---------------- h += proj rows 8.. (residual add) ----------------
__global__ void add_res_kernel(float* __restrict__ h, const float* __restrict__ proj)
{
    size_t e = (size_t)blockIdx.x*256 + threadIdx.x;
    if (e >= (size_t)BATCH*SEQ*DIMC) return;
    int c = e % DIMC; size_t r = e / DIMC;
    int tt = r % SEQ; int b = r / SEQ;
    h[e] += proj[((size_t)(b*NPAD + PAD0 + tt))*DIMC + c];
}

// ---------------- PPEG: transpose to image ----------------
__global__ void ppeg_im_kernel(const float* __restrict__ h, float* __restrict__ im)
{
    size_t e = (size_t)blockIdx.x*256 + threadIdx.x;
    if (e >= (size_t)BATCH*DIMC*NPIX) return;
    int p = e % NPIX; size_t r = e / NPIX;
    int c = r % DIMC; int b = r / DIMC;
    im[e] = h[((size_t)(b*SEQ) + 1 + p)*DIMC + c];
}

// ---------------- PPEG: 7/5/3 depthwise convs + identity, write back to h ----------------
__global__ void ppeg_conv_kernel(const float* __restrict__ im,
                                 const float* __restrict__ w7, const float* __restrict__ b7,
                                 const float* __restrict__ w5, const float* __restrict__ b5,
                                 const float* __restrict__ w3, const float* __restrict__ b3,
                                 float* __restrict__ h)
{
    int c = blockIdx.x; int b = blockIdx.y; int t = threadIdx.x; // 256
    __shared__ float img[NPIX];
    __shared__ float wf[49+25+9];
    const float* src = &im[((size_t)(b*DIMC+c))*NPIX];
    for (int p=t; p<NPIX; p+=256) img[p] = src[p];
    if (t < 49) wf[t] = w7[c*49+t];
    else if (t >= 64 && t < 64+25) wf[49 + (t-64)] = w5[c*25 + (t-64)];
    else if (t >= 96 && t < 96+9)  wf[74 + (t-96)] = w3[c*9 + (t-96)];
    __syncthreads();
    float bias = b7[c] + b5[c] + b3[c];
    for (int p=t; p<NPIX; p+=256) {
        int y = p/HS, x = p%HS;
        float acc = img[p] + bias;
        for (int dy=-3; dy<=3; ++dy){ int yy=y+dy; if (yy<0||yy>=HS) continue;
            for (int dx=-3; dx<=3; ++dx){ int xx=x+dx; if (xx<0||xx>=HS) continue;
                acc += wf[(dy+3)*7+(dx+3)]*img[yy*HS+xx]; } }
        for (int dy=-2; dy<=2; ++dy){ int yy=y+dy; if (yy<0||yy>=HS) continue;
            for (int dx=-2; dx<=2; ++dx){ int xx=x+dx; if (xx<0||xx>=HS) continue;
                acc += wf[49+(dy+2)*5+(dx+2)]*img[yy*HS+xx]; } }
        for (int dy=-1; dy<=1; ++dy){ int yy=y+dy; if (yy<0||yy>=HS) continue;
            for (int dx=-1; dx<=1; ++dx){ int xx=x+dx; if (xx<0||xx>=HS) continue;
                acc += wf[74+(dy+1)*3+(dx+1)]*img[yy*HS+xx]; } }
        h[((size_t)(b*SEQ)+1+p)*DIMC + c] = acc;
    }
}

// ---------------- final: LN(cls row) @ fc2 + bias -> logits ----------------
__global__ void final_kernel(const float* __restrict__ h, const float* __restrict__ g,
                             const float* __restrict__ bta, const float* __restrict__ fc2w,
                             const float* __restrict__ fc2b, float* __restrict__ out)
{
    int b = blockIdx.x; int t = threadIdx.x; // 512
    __shared__ float red[512];
    const float* x = &h[(size_t)b*SEQ*DIMC];
    float xv = x[t];
    red[t] = xv; __syncthreads();
    for (int s=256;s>0;s>>=1){ if(t<s) red[t]+=red[t+s]; __syncthreads(); }
    float mu = red[0]/512.f; __syncthreads();
    float d = xv - mu;
    red[t] = d*d; __syncthreads();
    for (int s=256;s>0;s>>=1){ if(t<s) red[t]+=red[t+s]; __syncthreads(); }
    float var = red[0]/512.f; __syncthreads();
    float hn = d * (1.f/sqrtf(var+1e-5f)) * g[t] + bta[t];
    for (int c=0;c<2;++c) {
        red[t] = hn * fc2w[t*2+c]; __syncthreads();
        for (int s=256;s>0;s>>=1){ if(t<s) red[t]+=red[t+s]; __syncthreads(); }
        if (t==0) out[b*2+c] = red[0] + fc2b[c];
        __syncthreads();
    }
}

// ================= host =================
extern "C" void kernel_launch(void* const* d_in, const int* in_sizes, int n_in,
                              void* d_out, int out_size, void* d_ws, size_t ws_size,
                              hipStream_t stream)
{
    (void)in_sizes; (void)n_in; (void)out_size; (void)ws_size;
    const float* feats = (const float*)d_in[0];
    const float* fc1_w = (const float*)d_in[1];
    const float* fc1_b = (const float*)d_in[2];
    const float* cls   = (const float*)d_in[3];
    const float* ln_g[2]  = {(const float*)d_in[4],  (const float*)d_in[10]};
    const float* ln_b[2]  = {(const float*)d_in[5],  (const float*)d_in[11]};
    const float* qkv_w[2] = {(const float*)d_in[6],  (const float*)d_in[12]};
    const float* out_w[2] = {(const float*)d_in[7],  (const float*)d_in[13]};
    const float* out_b[2] = {(const float*)d_in[8],  (const float*)d_in[14]};
    const float* res_w[2] = {(const float*)d_in[9],  (const float*)d_in[15]};
    const float* w7 = (const float*)d_in[16]; const float* b7 = (const float*)d_in[17];
    const float* w5 = (const float*)d_in[18]; const float* b5 = (const float*)d_in[19];
    const float* w3 = (const float*)d_in[20]; const float* b3 = (const float*)d_in[21];
    const float* ng = (const float*)d_in[22]; const float* nb = (const float*)d_in[23];
    const float* fc2w = (const float*)d_in[24]; const float* fc2b = (const float*)d_in[25];

    float* ws = (float*)d_ws;
    size_t off = 0;
    float* h    = ws + off; off += (size_t)BATCH*SEQ*DIMC;      // 2,167,808
    float* h0   = ws + off; off += (size_t)BATCH*NSEQ*DIMC;     // 2,097,152
    float* xp   = ws + off; off += (size_t)BATCH*NPAD*DIMC;     // 2,176,000
    float* qkv  = ws + off; off += (size_t)BATCH*NPAD*1536;     // 6,528,000 (aliased below)
    float* q    = ws + off; off += (size_t)BATCH*NH*NPAD*DHD;
    float* k    = ws + off; off += (size_t)BATCH*NH*NPAD*DHD;
    float* v    = ws + off; off += (size_t)BATCH*NH*NPAD*DHD;
    float* ql   = ws + off; off += (size_t)BATCH*NH*MLM*DHD;
    float* kl   = ws + off; off += (size_t)BATCH*NH*MLM*DHD;
    float* a1   = ws + off; off += (size_t)BATCH*NH*NPAD*MLM;
    float* a2   = ws + off; off += (size_t)BATCH*NH*MLM*MLM;
    float* a2i  = ws + off; off += (size_t)BATCH*NH*MLM*MLM;
    float* scal = ws + off; off += 16;
    float* a3   = ws + off; off += (size_t)BATCH*NH*MLM*NPAD;
    float* left = ws + off; off += (size_t)BATCH*NH*NPAD*MLM;
    float* a3v  = ws + off; off += (size_t)BATCH*NH*MLM*DHD;
    // aliases into dead qkv buffer (qkv dead after split_heads)
    float* hout = qkv;                               // 2,176,000
    float* proj = qkv + (size_t)BATCH*NPAD*DIMC;     // 2,176,000
    float* im   = qkv + (size_t)2*BATCH*NPAD*DIMC;   // 2,166,784 (fits in 6,528,000)

    float* outp = (float*)d_out;

    // FC1 + relu -> h0
    gemm_kernel<<<dim3(DIMC/64, (BATCH*NSEQ)/64), 256, 0, stream>>>(
        feats, fc1_w, fc1_b, h0, BATCH*NSEQ, DIMC, NIN, 1);
    // build h
    {
        size_t tot = (size_t)BATCH*SEQ*DIMC;
        buildh_kernel<<<(tot+255)/256, 256, 0, stream>>>(h0, cls, h);
    }

    for (int L = 0; L < 2; ++L) {
        float* aw = outp + 4 + (size_t)L*AWSZ;
        // LN -> xp (padded)
        ln_pad_kernel<<<dim3(NPAD, BATCH), 256, 0, stream>>>(h, ln_g[L], ln_b[L], xp);
        // qkv = xp @ qkv_w
        gemm_kernel<<<dim3(1536/64, (BATCH*NPAD+63)/64), 256, 0, stream>>>(
            xp, qkv_w[L], nullptr, qkv, BATCH*NPAD, 1536, DIMC, 0);
        // split heads
        {
            size_t tot = (size_t)BATCH*NH*NPAD*DHD;
            split_heads_kernel<<<(tot+255)/256, 256, 0, stream>>>(qkv, q, k, v);
        }
        landmark_kernel<<<dim3(MLM, NH, BATCH), 64, 0, stream>>>(q, k, ql, kl);
        a1_kernel<<<dim3(NPAD, NH, BATCH), 64, 0, stream>>>(q, kl, a1);
        a2_kernel<<<dim3(BATCH*NH), 320, 0, stream>>>(ql, kl, a2);
        a3_kernel<<<dim3(MLM, NH, BATCH), 256, 0, stream>>>(ql, k, a3);
        pinv_scale_kernel<<<1, 512, 0, stream>>>(a2, scal);
        pinv_kernel<<<BATCH*NH, 320, 0, stream>>>(a2, scal, a2i);
        left_kernel<<<dim3((NPAD*MLM+255)/256, NH, BATCH), 256, 0, stream>>>(a1, a2i, left);
        a3v_kernel<<<dim3(MLM, NH, BATCH), 64, 0, stream>>>(a3, v, a3v);
        headout_kernel<<<dim3(NPAD, NH, BATCH), 64, 0, stream>>>(left, a3v, v, res_w[L], hout);
        attn_out_kernel<<<dim3((NPAD+255)/256, NPAD, BATCH*NH), 256, 0, stream>>>(left, a3, aw);
        // proj = hout @ out_w + out_b
        gemm_kernel<<<dim3(DIMC/64, (BATCH*NPAD+63)/64), 256, 0, stream>>>(
            hout, out_w[L], out_b[L], proj, BATCH*NPAD, DIMC, DIMC, 0);
        // h += proj[rows 8..]
        {
            size_t tot = (size_t)BATCH*SEQ*DIMC;
            add_res_kernel<<<(tot+255)/256, 256, 0, stream>>>(h, proj);
        }
        if (L == 0) {
            // PPEG
            size_t tot = (size_t)BATCH*DIMC*NPIX;
            ppeg_im_kernel<<<(tot+255)/256, 256, 0, stream>>>(h, im);
            ppeg_conv_kernel<<<dim3(DIMC, BATCH), 256, 0, stream>>>(im, w7, b7, w5, b5, w3, b3, h);
        }
    }
    final_kernel<<<BATCH, 512, 0, stream>>>(h, ng, nb, fc2w, fc2b, outp);
}